// Round 11
// baseline (2885.685 us; speedup 1.0000x reference)
//
#include <hip/hip_runtime.h>

#define MAXBUK 1024         // fine buckets of 128 dst-nodes; n=100000 -> 782
#define PTILE 2048          // edges per k_part2b block
#define CAP   5120          // per-bucket capacity (mean 4092, +16 sigma)
#define BNODES 128          // nodes per bucket
#define APAD  65            // accum row stride in floats (bank spread)

typedef unsigned short ushort_t;
typedef unsigned int uint_t;

__device__ inline ushort_t f2bf(float f) {
    union { uint_t u; float f2; } c; c.f2 = f;
    uint_t r = c.u + 0x7FFFu + ((c.u >> 16) & 1u);   // round-to-nearest-even
    return (ushort_t)(r >> 16);
}

// ---------------- init per-bucket cursors ----------------
__global__ void k_init(int* __restrict__ bcur, int nbuk) {
    int t = threadIdx.x;
    if (t < nbuk) bcur[t] = t * CAP;
}

// ---------------- partition edges into capped bucket regions ----------------
// LDS-staged counting sort per 2048-edge tile; record: (dst & 127) << 24 | src.
__global__ __launch_bounds__(256) void k_part2b(
        const int* __restrict__ src, const int* __restrict__ dst,
        int* __restrict__ bcur, uint_t* __restrict__ ebuf, int E) {
    __shared__ int hcnt[MAXBUK];
    __shared__ int lbase[MAXBUK];
    __shared__ int gbase[MAXBUK];
    __shared__ int hcur[MAXBUK];
    __shared__ int psum[256];
    __shared__ uint_t stage[PTILE];
    __shared__ ushort_t sbuk[PTILE];
    int t = threadIdx.x;
    int base = blockIdx.x * PTILE;
    int end = base + PTILE; if (end > E) end = E;
    int cnt = end - base;
    #pragma unroll
    for (int j = 0; j < MAXBUK / 256; j++) { hcnt[t + j * 256] = 0; hcur[t + j * 256] = 0; }
    __syncthreads();
    // P1: tile histogram
    for (int i = base + t; i < end; i += 256)
        atomicAdd(&hcnt[dst[i] >> 7], 1);
    __syncthreads();
    // P2: exclusive scan of hcnt (4/thread) + global reservation
    int a0 = hcnt[4 * t], a1 = hcnt[4 * t + 1], a2 = hcnt[4 * t + 2], a3 = hcnt[4 * t + 3];
    int ps = a0 + a1 + a2 + a3;
    psum[t] = ps;
    __syncthreads();
    for (int off = 1; off < 256; off <<= 1) {
        int u = (t >= off) ? psum[t - off] : 0;
        __syncthreads();
        psum[t] += u;
        __syncthreads();
    }
    int ex = psum[t] - ps;
    lbase[4 * t]     = ex;
    lbase[4 * t + 1] = ex + a0;
    lbase[4 * t + 2] = ex + a0 + a1;
    lbase[4 * t + 3] = ex + a0 + a1 + a2;
    __syncthreads();
    #pragma unroll
    for (int j = 0; j < MAXBUK / 256; j++) {
        int bk = t + j * 256;
        int c = hcnt[bk];
        gbase[bk] = c ? atomicAdd(&bcur[bk], c) : 0;
    }
    __syncthreads();
    // P3: stage bucket-major in LDS
    for (int i = base + t; i < end; i += 256) {
        int d = dst[i];
        int bk = d >> 7;
        int p = atomicAdd(&hcur[bk], 1);
        int sp = lbase[bk] + p;
        stage[sp] = ((uint_t)(d & 127) << 24) | (uint_t)src[i];
        sbuk[sp] = (ushort_t)bk;
    }
    __syncthreads();
    // P4: coalesced copy-out (contiguous run per bucket)
    for (int i = t; i < cnt; i += 256) {
        int bk = sbuk[i];
        ebuf[gbase[bk] + (i - lbase[bk])] = stage[i];
    }
}

// ---------------- per-bucket degree -> dinv (hist only) ----------------
__global__ void k_deg(const uint_t* __restrict__ ebuf, const int* __restrict__ bend,
                      float* __restrict__ dinv, int n) {
    __shared__ int hist[BNODES];
    int b = blockIdx.x;
    int lo = b * CAP, hi = bend[b];
    int t = threadIdx.x;
    if (t < BNODES) hist[t] = 0;
    __syncthreads();
    for (int i = lo + t; i < hi; i += 256)
        atomicAdd(&hist[__builtin_nontemporal_load(&ebuf[i]) >> 24], 1);
    __syncthreads();
    int node = (b << 7) + t;
    if (t < BNODES && node < n)
        dinv[node] = rsqrtf((float)hist[t] + 1.0f);
}

// ---------------- tiled GEMM (vector-ALU f32, register blocking) ------------
template<int K, int H, bool SCALE, bool BIAS, bool OBF16>
__global__ __launch_bounds__(256) void k_gemm_t(
        const float* __restrict__ X, const float* __restrict__ W,
        const float* __restrict__ bias, const float* __restrict__ dinv,
        void* __restrict__ Yv, int n) {
    constexpr int COLV = H / 16;
    __shared__ float Ws[K * H];
    __shared__ float XsT[64][65];
    int tid = threadIdx.x;
    for (int i = tid; i < K * H; i += 256) Ws[i] = W[i];
    int tr = tid >> 4;
    int tc = tid & 15;
    int rowBase = blockIdx.x * 64;
    float acc[4][COLV];
    #pragma unroll
    for (int i = 0; i < 4; i++)
        #pragma unroll
        for (int c = 0; c < COLV; c++) acc[i][c] = 0.f;

    for (int kc = 0; kc < K; kc += 64) {
        __syncthreads();
        #pragma unroll
        for (int j = 0; j < 4; j++) {
            int flat = tid + j * 256;
            int row = flat >> 4;
            int kv  = flat & 15;
            int gr = rowBase + row;
            float4 v = make_float4(0.f, 0.f, 0.f, 0.f);
            if (gr < n)
                v = *reinterpret_cast<const float4*>(X + (size_t)gr * K + kc + kv * 4);
            XsT[kv * 4 + 0][row] = v.x;
            XsT[kv * 4 + 1][row] = v.y;
            XsT[kv * 4 + 2][row] = v.z;
            XsT[kv * 4 + 3][row] = v.w;
        }
        __syncthreads();
        #pragma unroll
        for (int k = 0; k < 64; k++) {
            float a0 = XsT[k][tr * 4 + 0];
            float a1 = XsT[k][tr * 4 + 1];
            float a2 = XsT[k][tr * 4 + 2];
            float a3 = XsT[k][tr * 4 + 3];
            const float* bp = &Ws[(kc + k) * H + tc * COLV];
            #pragma unroll
            for (int c = 0; c < COLV; c++) {
                float b = bp[c];
                acc[0][c] = fmaf(a0, b, acc[0][c]);
                acc[1][c] = fmaf(a1, b, acc[1][c]);
                acc[2][c] = fmaf(a2, b, acc[2][c]);
                acc[3][c] = fmaf(a3, b, acc[3][c]);
            }
        }
    }
    #pragma unroll
    for (int i = 0; i < 4; i++) {
        int row = rowBase + tr * 4 + i;
        if (row >= n) continue;
        float s = SCALE ? dinv[row] : 1.f;
        float v[COLV];
        #pragma unroll
        for (int c = 0; c < COLV; c++) {
            float t2 = acc[i][c];
            if (SCALE) t2 *= s;
            if (BIAS)  t2 += bias[tc * COLV + c];
            v[c] = t2;
        }
        if (OBF16) {
            ushort_t* Y = (ushort_t*)Yv;
            ushort4 pk;
            pk.x = f2bf(v[0]); pk.y = f2bf(v[1]);
            pk.z = f2bf(v[2]); pk.w = f2bf(v[3]);
            *reinterpret_cast<ushort4*>(Y + (size_t)row * H + tc * COLV) = pk;
        } else {
            float* Y = (float*)Yv;
            float* yp = Y + (size_t)row * H + tc * COLV;
            if (COLV == 4)      *reinterpret_cast<float4*>(yp) = make_float4(v[0], v[1], v[2], v[3]);
            else                *reinterpret_cast<float2*>(yp) = make_float2(v[0], v[1]);
        }
    }
}

// ---------------- Aggregation: destination-stationary LDS accumulators ------
// One block per 128-node bucket; acc[128][65] f32 in LDS initialized with the
// self-loop row. Edges consumed UNSORTED straight from the partition buffer:
// quarter q takes edge j+q (one ds_bpermute distributes 4 records), lane fp
// gathers uint2 (4 bf16 feats) of y[src] and ds_add_f32's into acc[dlow].
// 4 gathers in flight. Epilogue: relu(dinv*acc+bias), coalesced.
__global__ __launch_bounds__(512) void k_agg_lds(
        const uint_t* __restrict__ ebuf, const int* __restrict__ bend,
        const uint2* __restrict__ y2, const float* __restrict__ dinv,
        const float* __restrict__ bias, float* __restrict__ out, int n) {
    __shared__ float acc[BNODES * APAD];
    int b = blockIdx.x;
    int lo = b * CAP, hi = bend[b];
    int nodebase = b << 7;
    int t = threadIdx.x;
    int lane = t & 63;
    int wv = t >> 6;                 // wave 0..7
    int q = lane >> 4, fp = lane & 15;
    // init: acc row r <- y[nodebase+r] (self-loop), 4 threads per row
    {
        int r = t >> 2;              // 0..127
        int h = t & 3;               // quarter-row
        int node = nodebase + r;
        float* ap = &acc[r * APAD + h * 16];
        if (node < n) {
            #pragma unroll
            for (int k = 0; k < 4; k++) {
                uint2 u = y2[(size_t)node * 16 + h * 4 + k];
                ap[4 * k + 0] = __uint_as_float(u.x << 16);
                ap[4 * k + 1] = __uint_as_float(u.x & 0xFFFF0000u);
                ap[4 * k + 2] = __uint_as_float(u.y << 16);
                ap[4 * k + 3] = __uint_as_float(u.y & 0xFFFF0000u);
            }
        } else {
            #pragma unroll
            for (int k = 0; k < 16; k++) ap[k] = 0.f;
        }
    }
    __syncthreads();
    // edge loop: each wave owns 64-edge windows, stride 512
    for (int base = lo + wv * 64; base < hi; base += 512) {
        int wcnt = hi - base; if (wcnt > 64) wcnt = 64;
        int idx = (base + lane < hi) ? (int)__builtin_nontemporal_load(&ebuf[base + lane]) : 0;
        int j = 0;
        for (; j + 16 <= wcnt; j += 16) {
            uint_t e0 = (uint_t)__shfl(idx, j + q);
            uint_t e1 = (uint_t)__shfl(idx, j + 4 + q);
            uint_t e2 = (uint_t)__shfl(idx, j + 8 + q);
            uint_t e3 = (uint_t)__shfl(idx, j + 12 + q);
            uint2 u0 = y2[(size_t)(e0 & 0xFFFFFFu) * 16 + fp];
            uint2 u1 = y2[(size_t)(e1 & 0xFFFFFFu) * 16 + fp];
            uint2 u2 = y2[(size_t)(e2 & 0xFFFFFFu) * 16 + fp];
            uint2 u3 = y2[(size_t)(e3 & 0xFFFFFFu) * 16 + fp];
            float* p0 = &acc[(e0 >> 24) * APAD + 4 * fp];
            float* p1 = &acc[(e1 >> 24) * APAD + 4 * fp];
            float* p2 = &acc[(e2 >> 24) * APAD + 4 * fp];
            float* p3 = &acc[(e3 >> 24) * APAD + 4 * fp];
            atomicAdd(p0 + 0, __uint_as_float(u0.x << 16));
            atomicAdd(p0 + 1, __uint_as_float(u0.x & 0xFFFF0000u));
            atomicAdd(p0 + 2, __uint_as_float(u0.y << 16));
            atomicAdd(p0 + 3, __uint_as_float(u0.y & 0xFFFF0000u));
            atomicAdd(p1 + 0, __uint_as_float(u1.x << 16));
            atomicAdd(p1 + 1, __uint_as_float(u1.x & 0xFFFF0000u));
            atomicAdd(p1 + 2, __uint_as_float(u1.y << 16));
            atomicAdd(p1 + 3, __uint_as_float(u1.y & 0xFFFF0000u));
            atomicAdd(p2 + 0, __uint_as_float(u2.x << 16));
            atomicAdd(p2 + 1, __uint_as_float(u2.x & 0xFFFF0000u));
            atomicAdd(p2 + 2, __uint_as_float(u2.y << 16));
            atomicAdd(p2 + 3, __uint_as_float(u2.y & 0xFFFF0000u));
            atomicAdd(p3 + 0, __uint_as_float(u3.x << 16));
            atomicAdd(p3 + 1, __uint_as_float(u3.x & 0xFFFF0000u));
            atomicAdd(p3 + 2, __uint_as_float(u3.y << 16));
            atomicAdd(p3 + 3, __uint_as_float(u3.y & 0xFFFF0000u));
        }
        for (; j + 4 <= wcnt; j += 4) {
            uint_t e0 = (uint_t)__shfl(idx, j + q);
            uint2 u0 = y2[(size_t)(e0 & 0xFFFFFFu) * 16 + fp];
            float* p0 = &acc[(e0 >> 24) * APAD + 4 * fp];
            atomicAdd(p0 + 0, __uint_as_float(u0.x << 16));
            atomicAdd(p0 + 1, __uint_as_float(u0.x & 0xFFFF0000u));
            atomicAdd(p0 + 2, __uint_as_float(u0.y << 16));
            atomicAdd(p0 + 3, __uint_as_float(u0.y & 0xFFFF0000u));
        }
        if (j < wcnt) {
            int r2 = wcnt - j;
            uint_t e0 = (uint_t)__shfl(idx, j + (q < r2 ? q : 0));
            if (q < r2) {
                uint2 u0 = y2[(size_t)(e0 & 0xFFFFFFu) * 16 + fp];
                float* p0 = &acc[(e0 >> 24) * APAD + 4 * fp];
                atomicAdd(p0 + 0, __uint_as_float(u0.x << 16));
                atomicAdd(p0 + 1, __uint_as_float(u0.x & 0xFFFF0000u));
                atomicAdd(p0 + 2, __uint_as_float(u0.y << 16));
                atomicAdd(p0 + 3, __uint_as_float(u0.y & 0xFFFF0000u));
            }
        }
    }
    __syncthreads();
    // epilogue: out[node][f] = relu(dinv[node]*acc + bias[f]), coalesced
    for (int flat = t; flat < BNODES * 64; flat += 512) {
        int r = flat >> 6, f = flat & 63;
        int node = nodebase + r;
        if (node < n)
            out[(size_t)node * 64 + f] =
                fmaxf(fmaf(dinv[node], acc[r * APAD + f], bias[f]), 0.f);
    }
}

// ---------------- launch ----------------
extern "C" void kernel_launch(void* const* d_in, const int* in_sizes, int n_in,
                              void* d_out, int out_size, void* d_ws, size_t ws_size,
                              hipStream_t stream) {
    const float* x  = (const float*)d_in[0];
    const int*   ei = (const int*)d_in[1];
    const float* W1 = (const float*)d_in[2];
    const float* b1 = (const float*)d_in[3];
    const float* W2 = (const float*)d_in[4];
    const float* b2 = (const float*)d_in[5];
    const float* Wl = (const float*)d_in[6];
    const float* bl = (const float*)d_in[7];
    float* out = (float*)d_out;

    const int n = in_sizes[0] / 128;     // 100000
    const int E = in_sizes[1] / 2;       // 3200000
    const int* src = ei;
    const int* dst = ei + E;
    const int nbuk = (n + 127) >> 7;     // 782

    char* p = (char*)d_ws;
    auto alloc = [&](size_t bytes) { char* r = p; p += (bytes + 255) & ~(size_t)255; return r; };
    float* dinv   = (float*)alloc((size_t)n * 4);
    int*   bcur   = (int*)  alloc(MAXBUK * 4);
    uint_t* ebuf  = (uint_t*)alloc((size_t)nbuk * CAP * 4 + 256);
    ushort_t* bufY = (ushort_t*)alloc((size_t)n * 64 * 2);  // bf16 msg table L1
    float* bufA   = (float*)alloc((size_t)n * 64 * 4);      // f32 activations
    ushort_t* bufB = (ushort_t*)alloc((size_t)n * 64 * 2);  // bf16 msg table L2
    (void)ws_size;

    k_init<<<1, 1024, 0, stream>>>(bcur, nbuk);
    k_part2b<<<(E + PTILE - 1) / PTILE, 256, 0, stream>>>(src, dst, bcur, ebuf, E);
    k_deg<<<nbuk, 256, 0, stream>>>(ebuf, bcur, dinv, n);

    const int GB = (n + 63) / 64;

    // layer 1: y = dinv ⊙ (x @ W1) [bf16]; h1 = relu(dinv*agg + b1) [f32]
    k_gemm_t<128, 64, true, false, true><<<GB, 256, 0, stream>>>(x, W1, nullptr, dinv, bufY, n);
    k_agg_lds<<<nbuk, 512, 0, stream>>>(ebuf, bcur, (const uint2*)bufY, dinv, b1, bufA, n);

    // layer 2
    k_gemm_t<64, 64, true, false, true><<<GB, 256, 0, stream>>>(bufA, W2, nullptr, dinv, bufB, n);
    k_agg_lds<<<nbuk, 512, 0, stream>>>(ebuf, bcur, (const uint2*)bufB, dinv, b2, bufA, n);

    // head: out = h2 @ Wl + bl (f32)
    k_gemm_t<64, 32, false, true, false><<<GB, 256, 0, stream>>>(bufA, Wl, bl, nullptr, out, n);
}

// Round 12
// 346.544 us; speedup vs baseline: 8.3270x; 8.3270x over previous
//
#include <hip/hip_runtime.h>

#define MAXBUK 512          // buckets of 256 dst-nodes; n=100000 -> 391
#define PTILE 2048          // edges per k_part_ns block
#define CAP   10240         // per-bucket capacity (mean 8184, +22 sigma)

typedef unsigned short ushort_t;
typedef unsigned int uint_t;
typedef float v2f __attribute__((ext_vector_type(2)));

__device__ inline v2f unpk(uint_t u) {
    v2f r;
    r.x = __uint_as_float(u << 16);
    r.y = __uint_as_float(u & 0xFFFF0000u);
    return r;
}
__device__ inline ushort_t f2bf(float f) {
    union { uint_t u; float f2; } c; c.f2 = f;
    uint_t r = c.u + 0x7FFFu + ((c.u >> 16) & 1u);   // round-to-nearest-even
    return (ushort_t)(r >> 16);
}

// ---------------- init per-bucket cursors ----------------
__global__ void k_init(int* __restrict__ bcur, int nbuk) {
    int t = threadIdx.x;
    if (t < nbuk) bcur[t] = t * CAP;
}

// ---------------- partition: no-stage direct scatter ------------------------
// 6KB LDS -> high occupancy. Per 2048-edge tile: LDS hist, per-bucket global
// reservation, then scatter ebuf[gbase[bk] + hcur[bk]++] = (dlow<<24)|src.
// Runs are block-exclusive -> writes to a run stay in ONE XCD's L2 until the
// line is complete; only ~nbuk boundary lines per tile are cross-block.
__global__ __launch_bounds__(256) void k_part_ns(
        const int* __restrict__ src, const int* __restrict__ dst,
        int* __restrict__ bcur, uint_t* __restrict__ ebuf, int E) {
    __shared__ int hcnt[MAXBUK];
    __shared__ int gbase[MAXBUK];
    __shared__ int hcur[MAXBUK];
    int t = threadIdx.x;
    int base = blockIdx.x * PTILE;
    int end = base + PTILE; if (end > E) end = E;
    #pragma unroll
    for (int j = 0; j < MAXBUK / 256; j++) { hcnt[t + j * 256] = 0; hcur[t + j * 256] = 0; }
    __syncthreads();
    // P1: tile histogram
    for (int i = base + t; i < end; i += 256)
        atomicAdd(&hcnt[dst[i] >> 8], 1);
    __syncthreads();
    // P2: global reservation per bucket
    #pragma unroll
    for (int j = 0; j < MAXBUK / 256; j++) {
        int bk = t + j * 256;
        int c = hcnt[bk];
        gbase[bk] = c ? atomicAdd(&bcur[bk], c) : 0;
    }
    __syncthreads();
    // P3: direct scatter (4B records)
    for (int i = base + t; i < end; i += 256) {
        int d = dst[i];
        int bk = d >> 8;
        int p = atomicAdd(&hcur[bk], 1);
        ebuf[gbase[bk] + p] = ((uint_t)(d & 255) << 24) | (uint_t)src[i];
    }
}

// ---------------- per-bucket CSR assembly (one workgroup per bucket) --------
// 512 threads; hist/scan over the bucket's 256 nodes; scatter csr into the
// bucket's own 32KB region (single-L2 full-line evictions).
__global__ __launch_bounds__(512) void k_csr(
        const uint_t* __restrict__ ebuf, const int* __restrict__ bend,
        int* __restrict__ rowptr, int* __restrict__ rowend,
        float* __restrict__ dinv, int* __restrict__ csr, int n) {
    __shared__ int hist[256];
    __shared__ int scan[256];
    __shared__ int cur[256];
    int b = blockIdx.x;
    int lo = b * CAP, hi = bend[b];
    int nodebase = b << 8;
    int t = threadIdx.x;
    if (t < 256) hist[t] = 0;
    __syncthreads();
    for (int i = lo + t; i < hi; i += 512)
        atomicAdd(&hist[__builtin_nontemporal_load(&ebuf[i]) >> 24], 1);
    __syncthreads();
    int deg = 0;
    if (t < 256) { deg = hist[t]; scan[t] = deg; }
    __syncthreads();
    for (int off = 1; off < 256; off <<= 1) {
        int u = (t < 256 && t >= off) ? scan[t - off] : 0;
        __syncthreads();
        if (t < 256) scan[t] += u;
        __syncthreads();
    }
    if (t < 256) {
        int ex = scan[t] - deg;
        cur[t] = ex;
        int node = nodebase + t;
        if (node < n) {
            rowptr[node] = lo + ex;
            rowend[node] = lo + ex + deg;
            dinv[node] = rsqrtf((float)deg + 1.0f);
        }
    }
    __syncthreads();
    for (int i = lo + t; i < hi; i += 512) {
        uint_t e = __builtin_nontemporal_load(&ebuf[i]);
        int p = atomicAdd(&cur[e >> 24], 1);
        csr[lo + p] = (int)(e & 0xFFFFFFu);
    }
}

// ---------------- tiled GEMM (vector-ALU f32, register blocking) ------------
template<int K, int H, bool SCALE, bool BIAS, bool OBF16>
__global__ __launch_bounds__(256) void k_gemm_t(
        const float* __restrict__ X, const float* __restrict__ W,
        const float* __restrict__ bias, const float* __restrict__ dinv,
        void* __restrict__ Yv, int n) {
    constexpr int COLV = H / 16;
    __shared__ float Ws[K * H];
    __shared__ float XsT[64][65];
    int tid = threadIdx.x;
    for (int i = tid; i < K * H; i += 256) Ws[i] = W[i];
    int tr = tid >> 4;
    int tc = tid & 15;
    int rowBase = blockIdx.x * 64;
    float acc[4][COLV];
    #pragma unroll
    for (int i = 0; i < 4; i++)
        #pragma unroll
        for (int c = 0; c < COLV; c++) acc[i][c] = 0.f;

    for (int kc = 0; kc < K; kc += 64) {
        __syncthreads();
        #pragma unroll
        for (int j = 0; j < 4; j++) {
            int flat = tid + j * 256;
            int row = flat >> 4;
            int kv  = flat & 15;
            int gr = rowBase + row;
            float4 v = make_float4(0.f, 0.f, 0.f, 0.f);
            if (gr < n)
                v = *reinterpret_cast<const float4*>(X + (size_t)gr * K + kc + kv * 4);
            XsT[kv * 4 + 0][row] = v.x;
            XsT[kv * 4 + 1][row] = v.y;
            XsT[kv * 4 + 2][row] = v.z;
            XsT[kv * 4 + 3][row] = v.w;
        }
        __syncthreads();
        #pragma unroll
        for (int k = 0; k < 64; k++) {
            float a0 = XsT[k][tr * 4 + 0];
            float a1 = XsT[k][tr * 4 + 1];
            float a2 = XsT[k][tr * 4 + 2];
            float a3 = XsT[k][tr * 4 + 3];
            const float* bp = &Ws[(kc + k) * H + tc * COLV];
            #pragma unroll
            for (int c = 0; c < COLV; c++) {
                float b = bp[c];
                acc[0][c] = fmaf(a0, b, acc[0][c]);
                acc[1][c] = fmaf(a1, b, acc[1][c]);
                acc[2][c] = fmaf(a2, b, acc[2][c]);
                acc[3][c] = fmaf(a3, b, acc[3][c]);
            }
        }
    }
    #pragma unroll
    for (int i = 0; i < 4; i++) {
        int row = rowBase + tr * 4 + i;
        if (row >= n) continue;
        float s = SCALE ? dinv[row] : 1.f;
        float v[COLV];
        #pragma unroll
        for (int c = 0; c < COLV; c++) {
            float t2 = acc[i][c];
            if (SCALE) t2 *= s;
            if (BIAS)  t2 += bias[tc * COLV + c];
            v[c] = t2;
        }
        if (OBF16) {
            ushort_t* Y = (ushort_t*)Yv;
            ushort4 pk;
            pk.x = f2bf(v[0]); pk.y = f2bf(v[1]);
            pk.z = f2bf(v[2]); pk.w = f2bf(v[3]);
            *reinterpret_cast<ushort4*>(Y + (size_t)row * H + tc * COLV) = pk;
        } else {
            float* Y = (float*)Yv;
            float* yp = Y + (size_t)row * H + tc * COLV;
            if (COLV == 4)      *reinterpret_cast<float4*>(yp) = make_float4(v[0], v[1], v[2], v[3]);
            else                *reinterpret_cast<float2*>(yp) = make_float2(v[0], v[1]);
        }
    }
}

// ---------------- Aggregation: 4 edges per wave-gather, 4 loads in flight ----
__global__ void k_agg_bf(const int* __restrict__ rowptr, const int* __restrict__ rowend,
                         const int* __restrict__ csr, const uint2* __restrict__ y2,
                         const float* __restrict__ dinv, const float* __restrict__ bias,
                         float* __restrict__ out, int n) {
    int wave = (int)((blockIdx.x * (size_t)blockDim.x + threadIdx.x) >> 6);
    int lane = threadIdx.x & 63;
    if (wave >= n) return;
    int node = wave;
    int q  = lane >> 4;      // 0..3: edge slot within group of 4
    int fp = lane & 15;      // uint2 index within row (features 4fp..4fp+3)
    v2f a0 = {0.f, 0.f}, a1 = {0.f, 0.f}, a2 = {0.f, 0.f}, a3 = {0.f, 0.f};
    int s = rowptr[node], e = rowend[node];
    for (int base = s; base < e; base += 64) {
        int rem = e - base; int cnt = rem > 64 ? 64 : rem;
        int idx = (base + lane < e) ? __builtin_nontemporal_load(&csr[base + lane]) : 0;
        int j = 0;
        for (; j + 16 <= cnt; j += 16) {
            int s0 = __shfl(idx, j + q);
            int s1 = __shfl(idx, j + 4 + q);
            int s2 = __shfl(idx, j + 8 + q);
            int s3 = __shfl(idx, j + 12 + q);
            uint2 u0 = y2[(uint_t)s0 * 16 + fp];
            uint2 u1 = y2[(uint_t)s1 * 16 + fp];
            uint2 u2 = y2[(uint_t)s2 * 16 + fp];
            uint2 u3 = y2[(uint_t)s3 * 16 + fp];
            a0 += unpk(u0.x); a1 += unpk(u0.y);
            a2 += unpk(u1.x); a3 += unpk(u1.y);
            a0 += unpk(u2.x); a1 += unpk(u2.y);
            a2 += unpk(u3.x); a3 += unpk(u3.y);
        }
        for (; j + 8 <= cnt; j += 8) {
            int s0 = __shfl(idx, j + q);
            int s1 = __shfl(idx, j + 4 + q);
            uint2 u0 = y2[(uint_t)s0 * 16 + fp];
            uint2 u1 = y2[(uint_t)s1 * 16 + fp];
            a0 += unpk(u0.x); a1 += unpk(u0.y);
            a2 += unpk(u1.x); a3 += unpk(u1.y);
        }
        for (; j + 4 <= cnt; j += 4) {
            int s0 = __shfl(idx, j + q);
            uint2 u0 = y2[(uint_t)s0 * 16 + fp];
            a0 += unpk(u0.x); a1 += unpk(u0.y);
        }
        if (j < cnt) {
            int r2 = cnt - j;                    // 1..3 tail edges
            int s0 = __shfl(idx, j + (q < r2 ? q : 0));
            if (q < r2) {
                uint2 u0 = y2[(uint_t)s0 * 16 + fp];
                a0 += unpk(u0.x); a1 += unpk(u0.y);
            }
        }
    }
    a0 += a2; a1 += a3;
    float f0 = a0.x, f1 = a0.y, f2 = a1.x, f3 = a1.y;
    f0 += __shfl_xor(f0, 16); f0 += __shfl_xor(f0, 32);
    f1 += __shfl_xor(f1, 16); f1 += __shfl_xor(f1, 32);
    f2 += __shfl_xor(f2, 16); f2 += __shfl_xor(f2, 32);
    f3 += __shfl_xor(f3, 16); f3 += __shfl_xor(f3, 32);
    if (q == 0) {
        uint2 su = y2[(uint_t)node * 16 + fp];   // self-loop
        v2f s0 = unpk(su.x), s1 = unpk(su.y);
        f0 += s0.x; f1 += s0.y; f2 += s1.x; f3 += s1.y;
        float di = dinv[node];
        float4 b = *reinterpret_cast<const float4*>(bias + 4 * fp);
        float4 v;
        v.x = fmaxf(fmaf(di, f0, b.x), 0.f);
        v.y = fmaxf(fmaf(di, f1, b.y), 0.f);
        v.z = fmaxf(fmaf(di, f2, b.z), 0.f);
        v.w = fmaxf(fmaf(di, f3, b.w), 0.f);
        *reinterpret_cast<float4*>(out + (size_t)node * 64 + 4 * fp) = v;
    }
}

// ---------------- launch ----------------
extern "C" void kernel_launch(void* const* d_in, const int* in_sizes, int n_in,
                              void* d_out, int out_size, void* d_ws, size_t ws_size,
                              hipStream_t stream) {
    const float* x  = (const float*)d_in[0];
    const int*   ei = (const int*)d_in[1];
    const float* W1 = (const float*)d_in[2];
    const float* b1 = (const float*)d_in[3];
    const float* W2 = (const float*)d_in[4];
    const float* b2 = (const float*)d_in[5];
    const float* Wl = (const float*)d_in[6];
    const float* bl = (const float*)d_in[7];
    float* out = (float*)d_out;

    const int n = in_sizes[0] / 128;     // 100000
    const int E = in_sizes[1] / 2;       // 3200000
    const int* src = ei;
    const int* dst = ei + E;
    const int nbuk = (n + 255) >> 8;     // 391

    char* p = (char*)d_ws;
    auto alloc = [&](size_t bytes) { char* r = p; p += (bytes + 255) & ~(size_t)255; return r; };
    float* dinv   = (float*)alloc((size_t)n * 4);
    int*   bcur   = (int*)  alloc(MAXBUK * 4);
    int*   rowptr = (int*)  alloc((size_t)n * 4);
    int*   rowend = (int*)  alloc((size_t)n * 4);
    uint_t* ebuf  = (uint_t*)alloc((size_t)nbuk * CAP * 4 + 256);
    int*   csr    = (int*)  alloc((size_t)nbuk * CAP * 4 + 256);
    ushort_t* bufY = (ushort_t*)alloc((size_t)n * 64 * 2);  // bf16 msg table L1
    float* bufA   = (float*)alloc((size_t)n * 64 * 4);      // f32 activations
    ushort_t* bufB = (ushort_t*)alloc((size_t)n * 64 * 2);  // bf16 msg table L2
    (void)ws_size;

    k_init<<<1, 512, 0, stream>>>(bcur, nbuk);
    k_part_ns<<<(E + PTILE - 1) / PTILE, 256, 0, stream>>>(src, dst, bcur, ebuf, E);
    k_csr<<<nbuk, 512, 0, stream>>>(ebuf, bcur, rowptr, rowend, dinv, csr, n);

    const int GB = (n + 63) / 64;
    const int AB = (n + 3) / 4;

    // layer 1: y = dinv ⊙ (x @ W1) [bf16]; h1 = relu(dinv*agg + b1) [f32]
    k_gemm_t<128, 64, true, false, true><<<GB, 256, 0, stream>>>(x, W1, nullptr, dinv, bufY, n);
    k_agg_bf<<<AB, 256, 0, stream>>>(rowptr, rowend, csr, (const uint2*)bufY, dinv, b1, bufA, n);

    // layer 2
    k_gemm_t<64, 64, true, false, true><<<GB, 256, 0, stream>>>(bufA, W2, nullptr, dinv, bufB, n);
    k_agg_bf<<<AB, 256, 0, stream>>>(rowptr, rowend, csr, (const uint2*)bufB, dinv, b2, bufA, n);

    // head: out = h2 @ Wl + bl (f32)
    k_gemm_t<64, 32, false, true, false><<<GB, 256, 0, stream>>>(bufA, Wl, bl, nullptr, out, n);
}

// Round 13
// 285.724 us; speedup vs baseline: 10.0996x; 1.2129x over previous
//
#include <hip/hip_runtime.h>

#define MAXBUK 512          // buckets of 256 dst-nodes; n=100000 -> 391
#define NREP   8            // cursor/region replicas (spread reservation atomics)
#define PTILE  8192         // edges per k_part3 block
#define CAP_R  1536         // per-(replica,bucket) capacity (mean ~1023, +17 sigma)
#define CAPB   10240        // per-bucket csr capacity (mean 8184, +22 sigma)

typedef unsigned short ushort_t;
typedef unsigned int uint_t;
typedef float v2f __attribute__((ext_vector_type(2)));

__device__ inline v2f unpk(uint_t u) {
    v2f r;
    r.x = __uint_as_float(u << 16);
    r.y = __uint_as_float(u & 0xFFFF0000u);
    return r;
}
__device__ inline ushort_t f2bf(float f) {
    union { uint_t u; float f2; } c; c.f2 = f;
    uint_t r = c.u + 0x7FFFu + ((c.u >> 16) & 1u);   // round-to-nearest-even
    return (ushort_t)(r >> 16);
}

// ---------------- init replica cursors: bcur[i] = i*CAP_R ----------------
__global__ void k_init(int* __restrict__ bcur) {
    int i = blockIdx.x * blockDim.x + threadIdx.x;
    if (i < NREP * MAXBUK) bcur[i] = i * CAP_R;
}

// ---------------- partition: staged, replica-reserved, 8192-edge tiles ------
// record: (dst & 255) << 24 | src.  Replica = blockIdx & 7.
__global__ __launch_bounds__(512) void k_part3(
        const int* __restrict__ src, const int* __restrict__ dst,
        int* __restrict__ bcur, uint_t* __restrict__ ebuf, int E) {
    __shared__ int hcnt[MAXBUK];
    __shared__ int lbase[MAXBUK];
    __shared__ int gbase[MAXBUK];
    __shared__ int hcur[MAXBUK];
    __shared__ uint_t stage[PTILE];
    __shared__ ushort_t sbuk[PTILE];
    int t = threadIdx.x;
    int base = blockIdx.x * PTILE;
    int end = base + PTILE; if (end > E) end = E;
    int cnt = end - base;
    int rep = blockIdx.x & (NREP - 1);
    if (t < MAXBUK) { hcnt[t] = 0; hcur[t] = 0; }
    __syncthreads();
    // P1: dst -> regs, histogram
    int d[16];
    #pragma unroll
    for (int k = 0; k < 16; k++) {
        int i = base + t + k * 512;
        d[k] = (i < end) ? dst[i] : -1;
        if (d[k] >= 0) atomicAdd(&hcnt[d[k] >> 8], 1);
    }
    __syncthreads();
    // P2: inclusive scan of hcnt in lbase -> exclusive; global reservation
    if (t < MAXBUK) lbase[t] = hcnt[t];
    __syncthreads();
    for (int off = 1; off < MAXBUK; off <<= 1) {
        int u = (t < MAXBUK && t >= off) ? lbase[t - off] : 0;
        __syncthreads();
        if (t < MAXBUK) lbase[t] += u;
        __syncthreads();
    }
    int ex = 0;
    if (t < MAXBUK) ex = lbase[t] - hcnt[t];
    __syncthreads();
    if (t < MAXBUK) {
        lbase[t] = ex;
        int c = hcnt[t];
        gbase[t] = c ? atomicAdd(&bcur[(rep << 9) | t], c) : 0;
    }
    __syncthreads();
    // P3: stage bucket-major in LDS (src read coalesced here)
    #pragma unroll
    for (int k = 0; k < 16; k++) {
        if (d[k] >= 0) {
            int i = base + t + k * 512;
            int bk = d[k] >> 8;
            int p = atomicAdd(&hcur[bk], 1);
            int sp = lbase[bk] + p;
            stage[sp] = ((uint_t)(d[k] & 255) << 24) | (uint_t)src[i];
            sbuk[sp] = (ushort_t)bk;
        }
    }
    __syncthreads();
    // P4: coalesced copy-out (contiguous run per bucket in replica region)
    for (int i = t; i < cnt; i += 512) {
        int bk = sbuk[i];
        ebuf[gbase[bk] + (i - lbase[bk])] = stage[i];
    }
}

// ---------------- per-bucket CSR assembly from 8 replica runs ---------------
// One block per bucket: gather the 8 runs into a 40KB LDS stage (one coalesced
// global read), then hist/scan/scatter from LDS. Emits rowptr/rowend/dinv.
__global__ __launch_bounds__(512) void k_csr2(
        const uint_t* __restrict__ ebuf, const int* __restrict__ bcur,
        int* __restrict__ rowptr, int* __restrict__ rowend,
        float* __restrict__ dinv, int* __restrict__ csr, int n) {
    __shared__ uint_t stage[CAPB];
    __shared__ int hist[256];
    __shared__ int scan[256];
    __shared__ int cur[256];
    int b = blockIdx.x;
    int t = threadIdx.x;
    int lo = b * CAPB;
    int nodebase = b << 8;
    if (t < 256) hist[t] = 0;
    // gather replica runs into stage
    int tot = 0;
    #pragma unroll
    for (int r = 0; r < NREP; r++) {
        int rb = (r << 9) | b;
        int rbase = rb * CAP_R;
        int c = bcur[rb] - rbase;
        for (int i = t; i < c; i += 512)
            stage[tot + i] = __builtin_nontemporal_load(&ebuf[rbase + i]);
        tot += c;
    }
    __syncthreads();
    // hist
    for (int i = t; i < tot; i += 512)
        atomicAdd(&hist[stage[i] >> 24], 1);
    __syncthreads();
    int deg = 0;
    if (t < 256) { deg = hist[t]; scan[t] = deg; }
    __syncthreads();
    for (int off = 1; off < 256; off <<= 1) {
        int u = (t < 256 && t >= off) ? scan[t - off] : 0;
        __syncthreads();
        if (t < 256) scan[t] += u;
        __syncthreads();
    }
    if (t < 256) {
        int ex = scan[t] - deg;
        cur[t] = ex;
        int node = nodebase + t;
        if (node < n) {
            rowptr[node] = lo + ex;
            rowend[node] = lo + ex + deg;
            dinv[node] = rsqrtf((float)deg + 1.0f);
        }
    }
    __syncthreads();
    // scatter into this bucket's own csr region
    for (int i = t; i < tot; i += 512) {
        uint_t e = stage[i];
        int p = atomicAdd(&cur[e >> 24], 1);
        csr[lo + p] = (int)(e & 0xFFFFFFu);
    }
}

// ---------------- tiled GEMM (vector-ALU f32, register blocking) ------------
template<int K, int H, bool SCALE, bool BIAS, bool OBF16>
__global__ __launch_bounds__(256) void k_gemm_t(
        const float* __restrict__ X, const float* __restrict__ W,
        const float* __restrict__ bias, const float* __restrict__ dinv,
        void* __restrict__ Yv, int n) {
    constexpr int COLV = H / 16;
    __shared__ float Ws[K * H];
    __shared__ float XsT[64][65];
    int tid = threadIdx.x;
    for (int i = tid; i < K * H; i += 256) Ws[i] = W[i];
    int tr = tid >> 4;
    int tc = tid & 15;
    int rowBase = blockIdx.x * 64;
    float acc[4][COLV];
    #pragma unroll
    for (int i = 0; i < 4; i++)
        #pragma unroll
        for (int c = 0; c < COLV; c++) acc[i][c] = 0.f;

    for (int kc = 0; kc < K; kc += 64) {
        __syncthreads();
        #pragma unroll
        for (int j = 0; j < 4; j++) {
            int flat = tid + j * 256;
            int row = flat >> 4;
            int kv  = flat & 15;
            int gr = rowBase + row;
            float4 v = make_float4(0.f, 0.f, 0.f, 0.f);
            if (gr < n)
                v = *reinterpret_cast<const float4*>(X + (size_t)gr * K + kc + kv * 4);
            XsT[kv * 4 + 0][row] = v.x;
            XsT[kv * 4 + 1][row] = v.y;
            XsT[kv * 4 + 2][row] = v.z;
            XsT[kv * 4 + 3][row] = v.w;
        }
        __syncthreads();
        #pragma unroll
        for (int k = 0; k < 64; k++) {
            float a0 = XsT[k][tr * 4 + 0];
            float a1 = XsT[k][tr * 4 + 1];
            float a2 = XsT[k][tr * 4 + 2];
            float a3 = XsT[k][tr * 4 + 3];
            const float* bp = &Ws[(kc + k) * H + tc * COLV];
            #pragma unroll
            for (int c = 0; c < COLV; c++) {
                float b = bp[c];
                acc[0][c] = fmaf(a0, b, acc[0][c]);
                acc[1][c] = fmaf(a1, b, acc[1][c]);
                acc[2][c] = fmaf(a2, b, acc[2][c]);
                acc[3][c] = fmaf(a3, b, acc[3][c]);
            }
        }
    }
    #pragma unroll
    for (int i = 0; i < 4; i++) {
        int row = rowBase + tr * 4 + i;
        if (row >= n) continue;
        float s = SCALE ? dinv[row] : 1.f;
        float v[COLV];
        #pragma unroll
        for (int c = 0; c < COLV; c++) {
            float t2 = acc[i][c];
            if (SCALE) t2 *= s;
            if (BIAS)  t2 += bias[tc * COLV + c];
            v[c] = t2;
        }
        if (OBF16) {
            ushort_t* Y = (ushort_t*)Yv;
            ushort4 pk;
            pk.x = f2bf(v[0]); pk.y = f2bf(v[1]);
            pk.z = f2bf(v[2]); pk.w = f2bf(v[3]);
            *reinterpret_cast<ushort4*>(Y + (size_t)row * H + tc * COLV) = pk;
        } else {
            float* Y = (float*)Yv;
            float* yp = Y + (size_t)row * H + tc * COLV;
            if (COLV == 4)      *reinterpret_cast<float4*>(yp) = make_float4(v[0], v[1], v[2], v[3]);
            else                *reinterpret_cast<float2*>(yp) = make_float2(v[0], v[1]);
        }
    }
}

// ---------------- Aggregation: 4 edges per wave-gather, 4 loads in flight ----
__global__ void k_agg_bf(const int* __restrict__ rowptr, const int* __restrict__ rowend,
                         const int* __restrict__ csr, const uint2* __restrict__ y2,
                         const float* __restrict__ dinv, const float* __restrict__ bias,
                         float* __restrict__ out, int n) {
    int wave = (int)((blockIdx.x * (size_t)blockDim.x + threadIdx.x) >> 6);
    int lane = threadIdx.x & 63;
    if (wave >= n) return;
    int node = wave;
    int q  = lane >> 4;      // 0..3: edge slot within group of 4
    int fp = lane & 15;      // uint2 index within row (features 4fp..4fp+3)
    v2f a0 = {0.f, 0.f}, a1 = {0.f, 0.f}, a2 = {0.f, 0.f}, a3 = {0.f, 0.f};
    int s = rowptr[node], e = rowend[node];
    for (int base = s; base < e; base += 64) {
        int rem = e - base; int cnt = rem > 64 ? 64 : rem;
        int idx = (base + lane < e) ? __builtin_nontemporal_load(&csr[base + lane]) : 0;
        int j = 0;
        for (; j + 16 <= cnt; j += 16) {
            int s0 = __shfl(idx, j + q);
            int s1 = __shfl(idx, j + 4 + q);
            int s2 = __shfl(idx, j + 8 + q);
            int s3 = __shfl(idx, j + 12 + q);
            uint2 u0 = y2[(uint_t)s0 * 16 + fp];
            uint2 u1 = y2[(uint_t)s1 * 16 + fp];
            uint2 u2 = y2[(uint_t)s2 * 16 + fp];
            uint2 u3 = y2[(uint_t)s3 * 16 + fp];
            a0 += unpk(u0.x); a1 += unpk(u0.y);
            a2 += unpk(u1.x); a3 += unpk(u1.y);
            a0 += unpk(u2.x); a1 += unpk(u2.y);
            a2 += unpk(u3.x); a3 += unpk(u3.y);
        }
        for (; j + 8 <= cnt; j += 8) {
            int s0 = __shfl(idx, j + q);
            int s1 = __shfl(idx, j + 4 + q);
            uint2 u0 = y2[(uint_t)s0 * 16 + fp];
            uint2 u1 = y2[(uint_t)s1 * 16 + fp];
            a0 += unpk(u0.x); a1 += unpk(u0.y);
            a2 += unpk(u1.x); a3 += unpk(u1.y);
        }
        for (; j + 4 <= cnt; j += 4) {
            int s0 = __shfl(idx, j + q);
            uint2 u0 = y2[(uint_t)s0 * 16 + fp];
            a0 += unpk(u0.x); a1 += unpk(u0.y);
        }
        if (j < cnt) {
            int r2 = cnt - j;                    // 1..3 tail edges
            int s0 = __shfl(idx, j + (q < r2 ? q : 0));
            if (q < r2) {
                uint2 u0 = y2[(uint_t)s0 * 16 + fp];
                a0 += unpk(u0.x); a1 += unpk(u0.y);
            }
        }
    }
    a0 += a2; a1 += a3;
    float f0 = a0.x, f1 = a0.y, f2 = a1.x, f3 = a1.y;
    f0 += __shfl_xor(f0, 16); f0 += __shfl_xor(f0, 32);
    f1 += __shfl_xor(f1, 16); f1 += __shfl_xor(f1, 32);
    f2 += __shfl_xor(f2, 16); f2 += __shfl_xor(f2, 32);
    f3 += __shfl_xor(f3, 16); f3 += __shfl_xor(f3, 32);
    if (q == 0) {
        uint2 su = y2[(uint_t)node * 16 + fp];   // self-loop
        v2f s0 = unpk(su.x), s1 = unpk(su.y);
        f0 += s0.x; f1 += s0.y; f2 += s1.x; f3 += s1.y;
        float di = dinv[node];
        float4 b = *reinterpret_cast<const float4*>(bias + 4 * fp);
        float4 v;
        v.x = fmaxf(fmaf(di, f0, b.x), 0.f);
        v.y = fmaxf(fmaf(di, f1, b.y), 0.f);
        v.z = fmaxf(fmaf(di, f2, b.z), 0.f);
        v.w = fmaxf(fmaf(di, f3, b.w), 0.f);
        *reinterpret_cast<float4*>(out + (size_t)node * 64 + 4 * fp) = v;
    }
}

// ---------------- launch ----------------
extern "C" void kernel_launch(void* const* d_in, const int* in_sizes, int n_in,
                              void* d_out, int out_size, void* d_ws, size_t ws_size,
                              hipStream_t stream) {
    const float* x  = (const float*)d_in[0];
    const int*   ei = (const int*)d_in[1];
    const float* W1 = (const float*)d_in[2];
    const float* b1 = (const float*)d_in[3];
    const float* W2 = (const float*)d_in[4];
    const float* b2 = (const float*)d_in[5];
    const float* Wl = (const float*)d_in[6];
    const float* bl = (const float*)d_in[7];
    float* out = (float*)d_out;

    const int n = in_sizes[0] / 128;     // 100000
    const int E = in_sizes[1] / 2;       // 3200000
    const int* src = ei;
    const int* dst = ei + E;
    const int nbuk = (n + 255) >> 8;     // 391

    char* p = (char*)d_ws;
    auto alloc = [&](size_t bytes) { char* r = p; p += (bytes + 255) & ~(size_t)255; return r; };
    float* dinv   = (float*)alloc((size_t)n * 4);
    int*   bcur   = (int*)  alloc(NREP * MAXBUK * 4);
    int*   rowptr = (int*)  alloc((size_t)n * 4);
    int*   rowend = (int*)  alloc((size_t)n * 4);
    int*   csr    = (int*)  alloc((size_t)MAXBUK * CAPB * 4 + 256);
    ushort_t* bufY = (ushort_t*)alloc((size_t)n * 64 * 2);  // bf16 msg table L1
    float* bufA   = (float*)alloc((size_t)n * 64 * 4);      // f32 activations
    ushort_t* bufB = (ushort_t*)alloc((size_t)n * 64 * 2);  // bf16 msg table L2
    (void)ws_size;

    // ebuf (NREP*MAXBUK*CAP_R*4 = 25.2MB) aliases bufA (25.6MB): ebuf is dead
    // after k_csr2, before agg1 writes bufA.
    uint_t* ebuf = (uint_t*)bufA;

    k_init<<<(NREP * MAXBUK + 511) / 512, 512, 0, stream>>>(bcur);
    k_part3<<<(E + PTILE - 1) / PTILE, 512, 0, stream>>>(src, dst, bcur, ebuf, E);
    k_csr2<<<nbuk, 512, 0, stream>>>(ebuf, bcur, rowptr, rowend, dinv, csr, n);

    const int GB = (n + 63) / 64;
    const int AB = (n + 3) / 4;

    // layer 1: y = dinv ⊙ (x @ W1) [bf16]; h1 = relu(dinv*agg + b1) [f32]
    k_gemm_t<128, 64, true, false, true><<<GB, 256, 0, stream>>>(x, W1, nullptr, dinv, bufY, n);
    k_agg_bf<<<AB, 256, 0, stream>>>(rowptr, rowend, csr, (const uint2*)bufY, dinv, b1, bufA, n);

    // layer 2
    k_gemm_t<64, 64, true, false, true><<<GB, 256, 0, stream>>>(bufA, W2, nullptr, dinv, bufB, n);
    k_agg_bf<<<AB, 256, 0, stream>>>(rowptr, rowend, csr, (const uint2*)bufB, dinv, b2, bufA, n);

    // head: out = h2 @ Wl + bl (f32)
    k_gemm_t<64, 32, false, true, false><<<GB, 256, 0, stream>>>(bufA, Wl, bl, nullptr, out, n);
}

// Round 14
// 282.303 us; speedup vs baseline: 10.2220x; 1.0121x over previous
//
#include <hip/hip_runtime.h>

#define MAXBUK 512          // buckets of 256 dst-nodes; n=100000 -> 391
#define NREP   8            // cursor/region replicas (spread reservation atomics)
#define PTILE  8192         // edges per k_part3 block
#define CAP_R  1536         // per-(replica,bucket) capacity (mean ~1023, +17 sigma)
#define CAPB   10240        // per-bucket csr capacity (mean 8184, +22 sigma)

typedef unsigned short ushort_t;
typedef unsigned int uint_t;
typedef float v2f __attribute__((ext_vector_type(2)));

__device__ inline v2f unpk(uint_t u) {
    v2f r;
    r.x = __uint_as_float(u << 16);
    r.y = __uint_as_float(u & 0xFFFF0000u);
    return r;
}
__device__ inline ushort_t f2bf(float f) {
    union { uint_t u; float f2; } c; c.f2 = f;
    uint_t r = c.u + 0x7FFFu + ((c.u >> 16) & 1u);   // round-to-nearest-even
    return (ushort_t)(r >> 16);
}

// ---------------- init replica cursors: bcur[i] = i*CAP_R ----------------
__global__ void k_init(int* __restrict__ bcur) {
    int i = blockIdx.x * blockDim.x + threadIdx.x;
    if (i < NREP * MAXBUK) bcur[i] = i * CAP_R;
}

// ---------------- partition: staged, replica-reserved, 8192-edge tiles ------
// record: (dst & 255) << 24 | src.  Replica = blockIdx & 7.
__global__ __launch_bounds__(512) void k_part3(
        const int* __restrict__ src, const int* __restrict__ dst,
        int* __restrict__ bcur, uint_t* __restrict__ ebuf, int E) {
    __shared__ int hcnt[MAXBUK];
    __shared__ int lbase[MAXBUK];
    __shared__ int gbase[MAXBUK];
    __shared__ int hcur[MAXBUK];
    __shared__ uint_t stage[PTILE];
    __shared__ ushort_t sbuk[PTILE];
    int t = threadIdx.x;
    int base = blockIdx.x * PTILE;
    int end = base + PTILE; if (end > E) end = E;
    int cnt = end - base;
    int rep = blockIdx.x & (NREP - 1);
    if (t < MAXBUK) { hcnt[t] = 0; hcur[t] = 0; }
    __syncthreads();
    // P1: dst -> regs, histogram
    int d[16];
    #pragma unroll
    for (int k = 0; k < 16; k++) {
        int i = base + t + k * 512;
        d[k] = (i < end) ? dst[i] : -1;
        if (d[k] >= 0) atomicAdd(&hcnt[d[k] >> 8], 1);
    }
    __syncthreads();
    // P2: inclusive scan of hcnt in lbase -> exclusive; global reservation
    if (t < MAXBUK) lbase[t] = hcnt[t];
    __syncthreads();
    for (int off = 1; off < MAXBUK; off <<= 1) {
        int u = (t < MAXBUK && t >= off) ? lbase[t - off] : 0;
        __syncthreads();
        if (t < MAXBUK) lbase[t] += u;
        __syncthreads();
    }
    int ex = 0;
    if (t < MAXBUK) ex = lbase[t] - hcnt[t];
    __syncthreads();
    if (t < MAXBUK) {
        lbase[t] = ex;
        int c = hcnt[t];
        gbase[t] = c ? atomicAdd(&bcur[(rep << 9) | t], c) : 0;
    }
    __syncthreads();
    // P3: stage bucket-major in LDS (src read coalesced here)
    #pragma unroll
    for (int k = 0; k < 16; k++) {
        if (d[k] >= 0) {
            int i = base + t + k * 512;
            int bk = d[k] >> 8;
            int p = atomicAdd(&hcur[bk], 1);
            int sp = lbase[bk] + p;
            stage[sp] = ((uint_t)(d[k] & 255) << 24) | (uint_t)src[i];
            sbuk[sp] = (ushort_t)bk;
        }
    }
    __syncthreads();
    // P4: coalesced copy-out (contiguous run per bucket in replica region)
    for (int i = t; i < cnt; i += 512) {
        int bk = sbuk[i];
        ebuf[gbase[bk] + (i - lbase[bk])] = stage[i];
    }
}

// ---------------- per-bucket CSR assembly from 8 replica runs ---------------
__global__ __launch_bounds__(512) void k_csr2(
        const uint_t* __restrict__ ebuf, const int* __restrict__ bcur,
        int* __restrict__ rowptr, int* __restrict__ rowend,
        float* __restrict__ dinv, int* __restrict__ csr, int n) {
    __shared__ uint_t stage[CAPB];
    __shared__ int hist[256];
    __shared__ int scan[256];
    __shared__ int cur[256];
    int b = blockIdx.x;
    int t = threadIdx.x;
    int lo = b * CAPB;
    int nodebase = b << 8;
    if (t < 256) hist[t] = 0;
    // gather replica runs into stage
    int tot = 0;
    #pragma unroll
    for (int r = 0; r < NREP; r++) {
        int rb = (r << 9) | b;
        int rbase = rb * CAP_R;
        int c = bcur[rb] - rbase;
        for (int i = t; i < c; i += 512)
            stage[tot + i] = __builtin_nontemporal_load(&ebuf[rbase + i]);
        tot += c;
    }
    __syncthreads();
    // hist
    for (int i = t; i < tot; i += 512)
        atomicAdd(&hist[stage[i] >> 24], 1);
    __syncthreads();
    int deg = 0;
    if (t < 256) { deg = hist[t]; scan[t] = deg; }
    __syncthreads();
    for (int off = 1; off < 256; off <<= 1) {
        int u = (t < 256 && t >= off) ? scan[t - off] : 0;
        __syncthreads();
        if (t < 256) scan[t] += u;
        __syncthreads();
    }
    if (t < 256) {
        int ex = scan[t] - deg;
        cur[t] = ex;
        int node = nodebase + t;
        if (node < n) {
            rowptr[node] = lo + ex;
            rowend[node] = lo + ex + deg;
            dinv[node] = rsqrtf((float)deg + 1.0f);
        }
    }
    __syncthreads();
    // scatter into this bucket's own csr region
    for (int i = t; i < tot; i += 512) {
        uint_t e = stage[i];
        int p = atomicAdd(&cur[e >> 24], 1);
        csr[lo + p] = (int)(e & 0xFFFFFFu);
    }
}

// ---------------- tiled GEMM (vector-ALU f32, register blocking) ------------
template<int K, int H, bool SCALE, bool BIAS, bool OBF16>
__global__ __launch_bounds__(256) void k_gemm_t(
        const float* __restrict__ X, const float* __restrict__ W,
        const float* __restrict__ bias, const float* __restrict__ dinv,
        void* __restrict__ Yv, int n) {
    constexpr int COLV = H / 16;
    __shared__ float Ws[K * H];
    __shared__ float XsT[64][65];
    int tid = threadIdx.x;
    for (int i = tid; i < K * H; i += 256) Ws[i] = W[i];
    int tr = tid >> 4;
    int tc = tid & 15;
    int rowBase = blockIdx.x * 64;
    float acc[4][COLV];
    #pragma unroll
    for (int i = 0; i < 4; i++)
        #pragma unroll
        for (int c = 0; c < COLV; c++) acc[i][c] = 0.f;

    for (int kc = 0; kc < K; kc += 64) {
        __syncthreads();
        #pragma unroll
        for (int j = 0; j < 4; j++) {
            int flat = tid + j * 256;
            int row = flat >> 4;
            int kv  = flat & 15;
            int gr = rowBase + row;
            float4 v = make_float4(0.f, 0.f, 0.f, 0.f);
            if (gr < n)
                v = *reinterpret_cast<const float4*>(X + (size_t)gr * K + kc + kv * 4);
            XsT[kv * 4 + 0][row] = v.x;
            XsT[kv * 4 + 1][row] = v.y;
            XsT[kv * 4 + 2][row] = v.z;
            XsT[kv * 4 + 3][row] = v.w;
        }
        __syncthreads();
        #pragma unroll
        for (int k = 0; k < 64; k++) {
            float a0 = XsT[k][tr * 4 + 0];
            float a1 = XsT[k][tr * 4 + 1];
            float a2 = XsT[k][tr * 4 + 2];
            float a3 = XsT[k][tr * 4 + 3];
            const float* bp = &Ws[(kc + k) * H + tc * COLV];
            #pragma unroll
            for (int c = 0; c < COLV; c++) {
                float b = bp[c];
                acc[0][c] = fmaf(a0, b, acc[0][c]);
                acc[1][c] = fmaf(a1, b, acc[1][c]);
                acc[2][c] = fmaf(a2, b, acc[2][c]);
                acc[3][c] = fmaf(a3, b, acc[3][c]);
            }
        }
    }
    #pragma unroll
    for (int i = 0; i < 4; i++) {
        int row = rowBase + tr * 4 + i;
        if (row >= n) continue;
        float s = SCALE ? dinv[row] : 1.f;
        float v[COLV];
        #pragma unroll
        for (int c = 0; c < COLV; c++) {
            float t2 = acc[i][c];
            if (SCALE) t2 *= s;
            if (BIAS)  t2 += bias[tc * COLV + c];
            v[c] = t2;
        }
        if (OBF16) {
            ushort_t* Y = (ushort_t*)Yv;
            ushort4 pk;
            pk.x = f2bf(v[0]); pk.y = f2bf(v[1]);
            pk.z = f2bf(v[2]); pk.w = f2bf(v[3]);
            *reinterpret_cast<ushort4*>(Y + (size_t)row * H + tc * COLV) = pk;
        } else {
            float* Y = (float*)Yv;
            float* yp = Y + (size_t)row * H + tc * COLV;
            if (COLV == 4)      *reinterpret_cast<float4*>(yp) = make_float4(v[0], v[1], v[2], v[3]);
            else                *reinterpret_cast<float2*>(yp) = make_float2(v[0], v[1]);
        }
    }
}

// ---------------- Aggregation: 8 edges per wave-gather (oct layout) ----------
// o = lane>>3 picks the edge slot (ONE __shfl distributes 8 edge indices);
// fp = lane&7 picks a uint4 = 8 bf16 features. 32-edge main loop keeps 4x16B
// per lane in flight. f32 pk accumulate; 3-level shfl_xor reduce at the end.
__global__ void k_agg_bf(const int* __restrict__ rowptr, const int* __restrict__ rowend,
                         const int* __restrict__ csr, const uint4* __restrict__ y4,
                         const float* __restrict__ dinv, const float* __restrict__ bias,
                         float* __restrict__ out, int n) {
    int wave = (int)((blockIdx.x * (size_t)blockDim.x + threadIdx.x) >> 6);
    int lane = threadIdx.x & 63;
    if (wave >= n) return;
    int node = wave;
    int o  = lane >> 3;      // 0..7: edge slot within group of 8
    int fp = lane & 7;       // uint4 index within row (features 8fp..8fp+7)
    v2f a0 = {0.f, 0.f}, a1 = {0.f, 0.f}, a2 = {0.f, 0.f}, a3 = {0.f, 0.f};
    v2f b0 = {0.f, 0.f}, b1 = {0.f, 0.f}, b2 = {0.f, 0.f}, b3 = {0.f, 0.f};
    int s = rowptr[node], e = rowend[node];
    for (int base = s; base < e; base += 64) {
        int rem = e - base; int cnt = rem > 64 ? 64 : rem;
        int idx = (base + lane < e) ? __builtin_nontemporal_load(&csr[base + lane]) : 0;
        int j = 0;
        for (; j + 32 <= cnt; j += 32) {
            int s0 = __shfl(idx, j + o);
            int s1 = __shfl(idx, j + 8 + o);
            int s2 = __shfl(idx, j + 16 + o);
            int s3 = __shfl(idx, j + 24 + o);
            uint4 u0 = y4[(size_t)(uint_t)s0 * 8 + fp];
            uint4 u1 = y4[(size_t)(uint_t)s1 * 8 + fp];
            uint4 u2 = y4[(size_t)(uint_t)s2 * 8 + fp];
            uint4 u3 = y4[(size_t)(uint_t)s3 * 8 + fp];
            a0 += unpk(u0.x); a1 += unpk(u0.y); a2 += unpk(u0.z); a3 += unpk(u0.w);
            b0 += unpk(u1.x); b1 += unpk(u1.y); b2 += unpk(u1.z); b3 += unpk(u1.w);
            a0 += unpk(u2.x); a1 += unpk(u2.y); a2 += unpk(u2.z); a3 += unpk(u2.w);
            b0 += unpk(u3.x); b1 += unpk(u3.y); b2 += unpk(u3.z); b3 += unpk(u3.w);
        }
        for (; j + 16 <= cnt; j += 16) {
            int s0 = __shfl(idx, j + o);
            int s1 = __shfl(idx, j + 8 + o);
            uint4 u0 = y4[(size_t)(uint_t)s0 * 8 + fp];
            uint4 u1 = y4[(size_t)(uint_t)s1 * 8 + fp];
            a0 += unpk(u0.x); a1 += unpk(u0.y); a2 += unpk(u0.z); a3 += unpk(u0.w);
            b0 += unpk(u1.x); b1 += unpk(u1.y); b2 += unpk(u1.z); b3 += unpk(u1.w);
        }
        for (; j + 8 <= cnt; j += 8) {
            int s0 = __shfl(idx, j + o);
            uint4 u0 = y4[(size_t)(uint_t)s0 * 8 + fp];
            a0 += unpk(u0.x); a1 += unpk(u0.y); a2 += unpk(u0.z); a3 += unpk(u0.w);
        }
        if (j < cnt) {
            int r2 = cnt - j;                    // 1..7 tail edges
            int s0 = __shfl(idx, j + (o < r2 ? o : 0));
            if (o < r2) {
                uint4 u0 = y4[(size_t)(uint_t)s0 * 8 + fp];
                a0 += unpk(u0.x); a1 += unpk(u0.y); a2 += unpk(u0.z); a3 += unpk(u0.w);
            }
        }
    }
    a0 += b0; a1 += b1; a2 += b2; a3 += b3;
    float f0 = a0.x, f1 = a0.y, f2 = a1.x, f3 = a1.y;
    float f4 = a2.x, f5 = a2.y, f6 = a3.x, f7 = a3.y;
    f0 += __shfl_xor(f0, 8); f0 += __shfl_xor(f0, 16); f0 += __shfl_xor(f0, 32);
    f1 += __shfl_xor(f1, 8); f1 += __shfl_xor(f1, 16); f1 += __shfl_xor(f1, 32);
    f2 += __shfl_xor(f2, 8); f2 += __shfl_xor(f2, 16); f2 += __shfl_xor(f2, 32);
    f3 += __shfl_xor(f3, 8); f3 += __shfl_xor(f3, 16); f3 += __shfl_xor(f3, 32);
    f4 += __shfl_xor(f4, 8); f4 += __shfl_xor(f4, 16); f4 += __shfl_xor(f4, 32);
    f5 += __shfl_xor(f5, 8); f5 += __shfl_xor(f5, 16); f5 += __shfl_xor(f5, 32);
    f6 += __shfl_xor(f6, 8); f6 += __shfl_xor(f6, 16); f6 += __shfl_xor(f6, 32);
    f7 += __shfl_xor(f7, 8); f7 += __shfl_xor(f7, 16); f7 += __shfl_xor(f7, 32);
    if (o == 0) {
        uint4 su = y4[(size_t)node * 8 + fp];    // self-loop
        v2f s0 = unpk(su.x), s1 = unpk(su.y), s2 = unpk(su.z), s3 = unpk(su.w);
        f0 += s0.x; f1 += s0.y; f2 += s1.x; f3 += s1.y;
        f4 += s2.x; f5 += s2.y; f6 += s3.x; f7 += s3.y;
        float di = dinv[node];
        float4 c0 = *reinterpret_cast<const float4*>(bias + 8 * fp);
        float4 c1 = *reinterpret_cast<const float4*>(bias + 8 * fp + 4);
        float4 v0, v1;
        v0.x = fmaxf(fmaf(di, f0, c0.x), 0.f);
        v0.y = fmaxf(fmaf(di, f1, c0.y), 0.f);
        v0.z = fmaxf(fmaf(di, f2, c0.z), 0.f);
        v0.w = fmaxf(fmaf(di, f3, c0.w), 0.f);
        v1.x = fmaxf(fmaf(di, f4, c1.x), 0.f);
        v1.y = fmaxf(fmaf(di, f5, c1.y), 0.f);
        v1.z = fmaxf(fmaf(di, f6, c1.z), 0.f);
        v1.w = fmaxf(fmaf(di, f7, c1.w), 0.f);
        float* op = out + (size_t)node * 64 + 8 * fp;
        *reinterpret_cast<float4*>(op) = v0;
        *reinterpret_cast<float4*>(op + 4) = v1;
    }
}

// ---------------- launch ----------------
extern "C" void kernel_launch(void* const* d_in, const int* in_sizes, int n_in,
                              void* d_out, int out_size, void* d_ws, size_t ws_size,
                              hipStream_t stream) {
    const float* x  = (const float*)d_in[0];
    const int*   ei = (const int*)d_in[1];
    const float* W1 = (const float*)d_in[2];
    const float* b1 = (const float*)d_in[3];
    const float* W2 = (const float*)d_in[4];
    const float* b2 = (const float*)d_in[5];
    const float* Wl = (const float*)d_in[6];
    const float* bl = (const float*)d_in[7];
    float* out = (float*)d_out;

    const int n = in_sizes[0] / 128;     // 100000
    const int E = in_sizes[1] / 2;       // 3200000
    const int* src = ei;
    const int* dst = ei + E;
    const int nbuk = (n + 255) >> 8;     // 391

    char* p = (char*)d_ws;
    auto alloc = [&](size_t bytes) { char* r = p; p += (bytes + 255) & ~(size_t)255; return r; };
    float* dinv   = (float*)alloc((size_t)n * 4);
    int*   bcur   = (int*)  alloc(NREP * MAXBUK * 4);
    int*   rowptr = (int*)  alloc((size_t)n * 4);
    int*   rowend = (int*)  alloc((size_t)n * 4);
    int*   csr    = (int*)  alloc((size_t)MAXBUK * CAPB * 4 + 256);
    ushort_t* bufY = (ushort_t*)alloc((size_t)n * 64 * 2);  // bf16 msg table L1
    float* bufA   = (float*)alloc((size_t)n * 64 * 4);      // f32 activations
    ushort_t* bufB = (ushort_t*)alloc((size_t)n * 64 * 2);  // bf16 msg table L2
    (void)ws_size;

    // ebuf (NREP*MAXBUK*CAP_R*4 = 25.2MB) aliases bufA (25.6MB): ebuf is dead
    // after k_csr2, before agg1 writes bufA.
    uint_t* ebuf = (uint_t*)bufA;

    k_init<<<(NREP * MAXBUK + 511) / 512, 512, 0, stream>>>(bcur);
    k_part3<<<(E + PTILE - 1) / PTILE, 512, 0, stream>>>(src, dst, bcur, ebuf, E);
    k_csr2<<<nbuk, 512, 0, stream>>>(ebuf, bcur, rowptr, rowend, dinv, csr, n);

    const int GB = (n + 63) / 64;
    const int AB = (n + 3) / 4;

    // layer 1: y = dinv ⊙ (x @ W1) [bf16]; h1 = relu(dinv*agg + b1) [f32]
    k_gemm_t<128, 64, true, false, true><<<GB, 256, 0, stream>>>(x, W1, nullptr, dinv, bufY, n);
    k_agg_bf<<<AB, 256, 0, stream>>>(rowptr, rowend, csr, (const uint4*)bufY, dinv, b1, bufA, n);

    // layer 2
    k_gemm_t<64, 64, true, false, true><<<GB, 256, 0, stream>>>(bufA, W2, nullptr, dinv, bufB, n);
    k_agg_bf<<<AB, 256, 0, stream>>>(rowptr, rowend, csr, (const uint4*)bufB, dinv, b2, bufA, n);

    // head: out = h2 @ Wl + bl (f32)
    k_gemm_t<64, 32, false, true, false><<<GB, 256, 0, stream>>>(bufA, Wl, bl, nullptr, out, n);
}